// Round 1
// baseline (185.346 us; speedup 1.0000x reference)
//
#include <hip/hip_runtime.h>

// Problem constants (from setup_inputs)
constexpr int NROIS = 2000;
constexpr int Hh = 100, Ww = 100, Cc = 256;
constexpr int CH = 7, CW = 7;
constexpr int C4 = Cc / 4;  // 64 float4 per pixel -> one wave per output pixel

__global__ __launch_bounds__(256) void roi_crop_resize_kernel(
    const float* __restrict__ fm,    // [B, H, W, C]
    const float* __restrict__ rois,  // [N, 5] = (bidx, x1, y1, x2, y2) in pixel units
    float* __restrict__ out)         // [N, 7, 7, C]
{
    int idx = blockIdx.x * 256 + threadIdx.x;   // float4-granular output index
    int c4 = idx & (C4 - 1);                    // lane -> channel group (wave-uniform rest)
    int p  = idx >> 6;                          // output pixel: ((n*7+i)*7+j)
    int j  = p % CW;
    int t  = p / CW;
    int i  = t % CH;
    int n  = t / CH;

    const float* r = rois + (size_t)n * 5;
    int   b  = (int)r[0];
    // Match reference math order: normalize by /W,/H then *(dim-1)
    float x1 = r[1] / (float)Ww;
    float y1 = r[2] / (float)Hh;
    float x2 = r[3] / (float)Ww;
    float y2 = r[4] / (float)Hh;

    float in_y = y1 * (float)(Hh - 1)
               + (float)i * ((y2 - y1) * (float)(Hh - 1) / (float)(CH - 1));
    float in_x = x1 * (float)(Ww - 1)
               + (float)j * ((x2 - x1) * (float)(Ww - 1) / (float)(CW - 1));

    float4 o = make_float4(0.f, 0.f, 0.f, 0.f);

    // Wave-uniform validity (extrapolation value = 0)
    bool valid = (in_y >= 0.f) && (in_y <= (float)(Hh - 1)) &&
                 (in_x >= 0.f) && (in_x <= (float)(Ww - 1));
    if (valid) {
        float fy = floorf(in_y), fx = floorf(in_x);
        float ly = in_y - fy,    lx = in_x - fx;
        int ty = (int)fy;                         // valid => already in [0, H-1]
        int by = min(Hh - 1, (int)ceilf(in_y));
        int tx = (int)fx;
        int bx = min(Ww - 1, (int)ceilf(in_x));

        const float4* fm4 = (const float4*)fm;
        size_t base = (size_t)b * Hh * Ww;
        size_t rT = base + (size_t)ty * Ww;
        size_t rB = base + (size_t)by * Ww;

        float4 tl = fm4[(rT + tx) * C4 + c4];
        float4 tr = fm4[(rT + bx) * C4 + c4];
        float4 bl = fm4[(rB + tx) * C4 + c4];
        float4 br = fm4[(rB + bx) * C4 + c4];

        float4 top, bot;
        top.x = tl.x + (tr.x - tl.x) * lx;
        top.y = tl.y + (tr.y - tl.y) * lx;
        top.z = tl.z + (tr.z - tl.z) * lx;
        top.w = tl.w + (tr.w - tl.w) * lx;
        bot.x = bl.x + (br.x - bl.x) * lx;
        bot.y = bl.y + (br.y - bl.y) * lx;
        bot.z = bl.z + (br.z - bl.z) * lx;
        bot.w = bl.w + (br.w - bl.w) * lx;
        o.x = top.x + (bot.x - top.x) * ly;
        o.y = top.y + (bot.y - top.y) * ly;
        o.z = top.z + (bot.z - top.z) * ly;
        o.w = top.w + (bot.w - top.w) * ly;
    }
    ((float4*)out)[(size_t)p * C4 + c4] = o;
}

extern "C" void kernel_launch(void* const* d_in, const int* in_sizes, int n_in,
                              void* d_out, int out_size, void* d_ws, size_t ws_size,
                              hipStream_t stream) {
    const float* fm   = (const float*)d_in[0];   // [8,100,100,256] fp32
    const float* rois = (const float*)d_in[1];   // [2000,5] fp32
    float* out = (float*)d_out;                  // [2000,7,7,256] fp32

    constexpr int total4  = NROIS * CH * CW * C4;   // 6,272,000 float4 outputs
    constexpr int threads = 256;
    constexpr int blocks  = total4 / threads;        // 24,500 (exact)
    roi_crop_resize_kernel<<<blocks, threads, 0, stream>>>(fm, rois, out);
}